// Round 8
// baseline (229.690 us; speedup 1.0000x reference)
//
#include <hip/hip_runtime.h>

typedef unsigned short u16t;
typedef short short8 __attribute__((ext_vector_type(8)));
typedef float f32x4 __attribute__((ext_vector_type(4)));
typedef float f32x2 __attribute__((ext_vector_type(2)));

__device__ __forceinline__ u16t f2bf_rne(float f) {
  unsigned u = __builtin_bit_cast(unsigned, f);
  u += 0x7FFFu + ((u >> 16) & 1u);
  return (u16t)(u >> 16);
}
// pack two fp32 -> bf16 pair (round-half-up: same 0.5-ulp bound as RNE, 5 VALU)
__device__ __forceinline__ unsigned pk2(float a, float b) {
  unsigned ua = __builtin_bit_cast(unsigned, a) + 0x8000u;
  unsigned ub = __builtin_bit_cast(unsigned, b) + 0x8000u;
  return (ua >> 16) | (ub & 0xFFFF0000u);
}
union S8U { short8 s; unsigned w[4]; };
__device__ __forceinline__ short8 pack8f(float4 a, float4 b) {
  S8U u;
  u.w[0] = pk2(a.x, a.y); u.w[1] = pk2(a.z, a.w);
  u.w[2] = pk2(b.x, b.y); u.w[3] = pk2(b.z, b.w);
  return u.s;
}

// Weight table layout in d_ws (16B-aligned). SWAPPED-OPERAND scheme:
// main kernel computes mfma(A=weights, B=data) -> D[row=n(quad,j)][col=r(l15)].
//   WB : [p][nt][half][lane] short8 (16B)   = 32768 B  (W1 frags, k-rows 4..67)
//   BS : [p][nt][l15] short8 (16B)          =  4096 B  (sin cols k 64..67; slot[4] = b1[n]/s1
//                                                       -> bias rides the MFMA via aS[4]=1.0;
//                                                       slots 5..7 zero; quad-broadcast)
//   FQ : [p][nt][quad][2] f32x4 (16B)       =  2048 B  (t0={w0[j=0..3]}, t1={w1[j=0..3]},
//                                                       wo[j]=W2o[n]*sq2*s1, n=nt*16+quad*4+j)
//   --- staged to LDS: first 38912 B ---
//   BC : [p][half][lane] short8 (16B)       =  4096 B  (W2 c-col frags; rows>=2 zeroed; global/L2)
#define WS_WB  0
#define WS_BS  32768
#define WS_FQ  36864
#define LDS_BYTES 38912
#define WS_BC  38912
#define WS_BYTES 43008

// ---------------- prep: convert + permute weights into d_ws (16 small blocks) ----
__global__ void prep_kernel(const float* __restrict__ Wx1, const float* __restrict__ bx1,
                            const float* __restrict__ Wx2,
                            const float* __restrict__ Wy1, const float* __restrict__ by1,
                            const float* __restrict__ Wy2,
                            char* __restrict__ ws)
{
  const int b = blockIdx.x;            // 16 blocks: (p, nt)
  const int lane = threadIdx.x;        // 64 threads = 1 wave
  const int p = b >> 3, nt = b & 7;
  const int l15 = lane & 15, quad = lane >> 4;
  const float* W1 = p ? Wy1 : Wx1;
  const float* B1 = p ? by1 : bx1;
  const float* W2 = p ? Wy2 : Wx2;
  const int n = nt * 16 + l15;
  const float* rp = W1 + n * 68;
  short8 bb0, bb1;
  #pragma unroll
  for (int j = 0; j < 8; ++j) {
    bb0[j] = (short)f2bf_rne(rp[4 + quad * 8 + j]);    // K-perm: k<64 -> col 4+k (c dims)
    bb1[j] = (short)f2bf_rne(rp[36 + quad * 8 + j]);   // k 32..63 -> col 36+...
  }
  short8* wb = (short8*)(ws + WS_WB);
  wb[((p * 8 + nt) * 2 + 0) * 64 + lane] = bb0;
  wb[((p * 8 + nt) * 2 + 1) * 64 + lane] = bb1;

  if (quad == 0) {   // sin-col weights (k 64..67) for neuron n; slot 4 carries b1[n]/s1
    const float inv_s1 = 8.24621125123532110f; // sqrt(68)
    short8 t = (short8)0;
    #pragma unroll
    for (int j = 0; j < 4; ++j) t[j] = (short)f2bf_rne(rp[j]);
    t[4] = (short)f2bf_rne(B1[n] * inv_s1);    // pairs with aS[4] = 1.0 in main
    ((short8*)(ws + WS_BS))[(p * 8 + nt) * 16 + l15] = t;
  }

  if (lane < 8) {    // FQ scalars, indexed by the OUTPUT n = nt*16 + quad*4 + j
    const int q = lane >> 1, t = lane & 1;
    const float SQ2 = 1.41421356237309515f;
    const float s1 = 0.121267812518166f;       // 1/sqrt(68)
    float4 v;
    #pragma unroll
    for (int j = 0; j < 4; ++j) {
      const int nn = nt * 16 + q * 4 + j;
      ((float*)&v)[j] = W2[(t ? 192 : 0) + nn] * SQ2 * s1;
    }
    ((float4*)(ws + WS_FQ))[((p * 8 + nt) * 4 + q) * 2 + t] = v;
  }

  if (b < 4) {       // W2 c-columns (128..191); rows l15>=2 zero -> D rows 2..15 = 0
    const int p2 = b >> 1, h = b & 1;
    const float* W2b = p2 ? Wy2 : Wx2;
    short8 bc = (short8)0;
    if (l15 < 2) {
      #pragma unroll
      for (int j = 0; j < 8; ++j)
        bc[j] = (short)f2bf_rne(W2b[l15 * 192 + 128 + h * 32 + quad * 8 + j]);
    }
    ((short8*)(ws + WS_BC))[(p2 * 2 + h) * 64 + lane] = bc;
  }
}

// ------- main: 512-thr blocks, mt=2; bias-in-MFMA, c-part hoisted, paths unrolled ----
__global__ __launch_bounds__(512, 2)
void icb_main(const float* __restrict__ g_coords, const float* __restrict__ g_c,
              const float* __restrict__ g_bx2, const float* __restrict__ g_by2,
              const char* __restrict__ ws, float* __restrict__ g_out)
{
  __shared__ float4 s_tab4[LDS_BYTES / 16];   // 38912 B -> 4 blocks/CU by LDS
  char* s_tab = (char*)s_tab4;

  const int tid  = threadIdx.x;
  const int lane = tid & 63, wave = tid >> 6;          // 8 waves
  const int l15  = lane & 15, quad = lane >> 4;
  const int wbase = blockIdx.x * 256 + wave * 32;      // 2 m-tiles of 16 rows per wave

  // ---- 1. per-row global loads first: latency overlaps staging ----
  float4 ra[2][4]; float2 rco[2];
  #pragma unroll
  for (int mt = 0; mt < 2; ++mt) {
    const int r = wbase + mt * 16 + l15;
    const float4* cr = (const float4*)(g_c + (size_t)r * 64);
    ra[mt][0] = cr[quad * 2];     ra[mt][1] = cr[quad * 2 + 1];
    ra[mt][2] = cr[8 + quad * 2]; ra[mt][3] = cr[8 + quad * 2 + 1];
    rco[mt] = ((const float2*)g_coords)[r];
  }

  // ---- 2. stage the weight table into LDS (once per block) ----
  {
    const float4* src = (const float4*)ws;
    #pragma unroll
    for (int k = 0; k < 5; ++k) {
      const int t = tid + k * 512;                     // 2432 x 16B
      if (t < LDS_BYTES / 16) s_tab4[t] = src[t];
    }
  }

  // both paths' W2-c frags (L2-resident, 16B each) issued once, up front
  const short8* wbc = (const short8*)(ws + WS_BC);
  short8 bcA0 = wbc[0 * 64 + lane], bcA1 = wbc[1 * 64 + lane];
  short8 bcB0 = wbc[2 * 64 + lane], bcB1 = wbc[3 * 64 + lane];
  const float gb20x = g_bx2[0], gb21x = g_bx2[1];
  const float gb20y = g_by2[0], gb21y = g_by2[1];

  // ---- 3. pack data frags (B-operands) while staging drains ----
  short8 aC0[2], aC1[2];
  float xold[2], yold[2];
  #pragma unroll
  for (int mt = 0; mt < 2; ++mt) {
    aC0[mt] = pack8f(ra[mt][0], ra[mt][1]);
    aC1[mt] = pack8f(ra[mt][2], ra[mt][3]);
    xold[mt] = rco[mt].x; yold[mt] = rco[mt].y;
  }

  __syncthreads();

  const short8* wb  = (const short8*)(s_tab + WS_WB);
  const short8* wbs = (const short8*)(s_tab + WS_BS);
  const f32x4*  wfq = (const f32x4*) (s_tab + WS_FQ);

  const float s2 = 0.0721687836487032f;   // 1/sqrt(192)

  float vin[2], xnew[2], ynew[2], xls[2], yls[2];
  vin[0] = xold[0]; vin[1] = xold[1];

  #pragma unroll                           // FULL unroll: static bc/b2/pb per copy
  for (int path = 0; path < 2; ++path) {
    const int pb = path * 8;
    const float b20 = path ? gb20y : gb20x;
    const float b21 = path ? gb21y : gb21x;
    const short8 bc0 = path ? bcB0 : bcA0;
    const short8 bc1 = path ? bcB1 : bcA1;

    // sinusoidal data frag: quad 0 holds k 64..67 = [sin a, sin 2a, cos a, c2a], slot4 = 1.0
    short8 aS[2];
    #pragma unroll
    for (int mt = 0; mt < 2; ++mt) {
      short8 f = (short8)0;
      if (quad == 0) {
        float a = vin[mt] * 0.1f;
        float sa, ca;
        __sincosf(a, &sa, &ca);
        float s2a = 2.0f * sa * ca;
        float c2a = 1.0f - 2.0f * sa * sa;
        f[0] = (short)f2bf_rne(sa); f[1] = (short)f2bf_rne(s2a);
        f[2] = (short)f2bf_rne(ca); f[3] = (short)f2bf_rne(c2a);
        f[4] = (short)0x3F80;              // 1.0 -> picks up b1[n]/s1 from bsw[4]
      }
      aS[mt] = f;
    }

    // c-part first: register-only MFMAs fill the first ds_read latency window.
    // D rows >= 2 are zero by construction; rows 0/1 seed the hp partials.
    f32x2 hp0[2], hp1[2];
    #pragma unroll
    for (int mt = 0; mt < 2; ++mt) {
      f32x4 a = {0.f, 0.f, 0.f, 0.f};
      a = __builtin_amdgcn_mfma_f32_16x16x32_bf16(bc0, aC0[mt], a, 0, 0, 0);
      a = __builtin_amdgcn_mfma_f32_16x16x32_bf16(bc1, aC1[mt], a, 0, 0, 0);
      hp0[mt][0] = a[0]; hp0[mt][1] = 0.f;
      hp1[mt][0] = a[1]; hp1[mt][1] = 0.f;
    }

    #pragma unroll 2
    for (int nt = 0; nt < 8; ++nt) {
      short8 bb0 = wb[((pb + nt) * 2 + 0) * 64 + lane];
      short8 bb1 = wb[((pb + nt) * 2 + 1) * 64 + lane];
      short8 bsw = wbs[(pb + nt) * 16 + l15];            // broadcast across quads
      const f32x4* fq = wfq + ((pb + nt) * 4 + quad) * 2;
      f32x4 w0q = fq[0], w1q = fq[1];                    // w = W2*sq2*s1 per (quad,j)
      f32x2 w0lo = {w0q[0], w0q[1]}, w0hi = {w0q[2], w0q[3]};
      f32x2 w1lo = {w1q[0], w1q[1]}, w1hi = {w1q[2], w1q[3]};
      #pragma unroll
      for (int mt = 0; mt < 2; ++mt) {
        f32x4 acc = {0.f, 0.f, 0.f, 0.f};
        acc = __builtin_amdgcn_mfma_f32_16x16x32_bf16(bb0, aC0[mt], acc, 0, 0, 0);
        acc = __builtin_amdgcn_mfma_f32_16x16x32_bf16(bb1, aC1[mt], acc, 0, 0, 0);
        acc = __builtin_amdgcn_mfma_f32_16x16x32_bf16(bsw, aS[mt],  acc, 0, 0, 0);
        // m = max(D, 0.2*D) = leaky(D + b1/s1); true h = s1*m, s1 folded into w*
        f32x2 dlo = {acc[0], acc[1]}, dhi = {acc[2], acc[3]};
        f32x2 mlo = __builtin_elementwise_max(dlo, dlo * 0.2f);
        f32x2 mhi = __builtin_elementwise_max(dhi, dhi * 0.2f);
        hp0[mt] = __builtin_elementwise_fma(mlo, w0lo, hp0[mt]);
        hp0[mt] = __builtin_elementwise_fma(mhi, w0hi, hp0[mt]);
        hp1[mt] = __builtin_elementwise_fma(mlo, w1lo, hp1[mt]);
        hp1[mt] = __builtin_elementwise_fma(mhi, w1hi, hp1[mt]);
      }
    }

    // combine pair-partials, reduce across the 4 quads (2-stage butterfly)
    #pragma unroll
    for (int mt = 0; mt < 2; ++mt) {
      float h0 = hp0[mt][0] + hp0[mt][1];
      float h1 = hp1[mt][0] + hp1[mt][1];
      h0 += __shfl_xor(h0, 16); h0 += __shfl_xor(h0, 32);
      h1 += __shfl_xor(h1, 16); h1 += __shfl_xor(h1, 32);

      float lsraw = fmaf(s2, h0, b20);
      float brow  = fmaf(s2, h1, b21);
      float ls = fminf(fmaxf(lsraw, -5.f), 5.f);
      float e  = __expf(ls);
      if (path == 0) {
        yls[mt]  = ls;
        ynew[mt] = fmaf(yold[mt], e, brow);
        vin[mt]  = ynew[mt];          // y-path sinusoidals use updated y (all lanes have it)
      } else {
        xls[mt]  = ls;
        xnew[mt] = fmaf(xold[mt], e, brow);
      }
    }
  }

  // outputs: warped (x,y) then log_jac, fp32; every lane l15 holds its row's result
  if (lane < 16) {
    #pragma unroll
    for (int mt = 0; mt < 2; ++mt) {
      int R = wbase + mt * 16 + lane;
      float2 pw; pw.x = xnew[mt]; pw.y = ynew[mt];
      reinterpret_cast<float2*>(g_out)[R] = pw;
      g_out[1048576 + R] = xls[mt] + yls[mt];
    }
  }
}

extern "C" void kernel_launch(void* const* d_in, const int* in_sizes, int n_in,
                              void* d_out, int out_size, void* d_ws, size_t ws_size,
                              hipStream_t stream) {
  (void)in_sizes; (void)n_in; (void)out_size; (void)ws_size;
  prep_kernel<<<16, 64, 0, stream>>>(
      (const float*)d_in[2], (const float*)d_in[3], (const float*)d_in[4],
      (const float*)d_in[6], (const float*)d_in[7], (const float*)d_in[8],
      (char*)d_ws);
  icb_main<<<2048, 512, 0, stream>>>(
      (const float*)d_in[0], (const float*)d_in[1],
      (const float*)d_in[5], (const float*)d_in[9],
      (const char*)d_ws, (float*)d_out);
}

// Round 9
// 224.424 us; speedup vs baseline: 1.0235x; 1.0235x over previous
//
#include <hip/hip_runtime.h>

typedef unsigned short u16t;
typedef short short8 __attribute__((ext_vector_type(8)));
typedef float f32x4 __attribute__((ext_vector_type(4)));
typedef float f32x2 __attribute__((ext_vector_type(2)));

__device__ __forceinline__ u16t f2bf_rne(float f) {
  unsigned u = __builtin_bit_cast(unsigned, f);
  u += 0x7FFFu + ((u >> 16) & 1u);
  return (u16t)(u >> 16);
}
// pack two fp32 -> bf16 pair (round-half-up: same 0.5-ulp bound as RNE, 5 VALU)
__device__ __forceinline__ unsigned pk2(float a, float b) {
  unsigned ua = __builtin_bit_cast(unsigned, a) + 0x8000u;
  unsigned ub = __builtin_bit_cast(unsigned, b) + 0x8000u;
  return (ua >> 16) | (ub & 0xFFFF0000u);
}
union S8U { short8 s; unsigned w[4]; };
__device__ __forceinline__ short8 pack8f(float4 a, float4 b) {
  S8U u;
  u.w[0] = pk2(a.x, a.y); u.w[1] = pk2(a.z, a.w);
  u.w[2] = pk2(b.x, b.y); u.w[3] = pk2(b.z, b.w);
  return u.s;
}

// Weight table layout in d_ws (16B-aligned). SWAPPED-OPERAND scheme:
// main kernel computes mfma(A=weights, B=data) -> D[row=n(quad,j)][col=r(l15)].
//   WB : [p][nt][half][lane] short8 (16B)   = 32768 B  (W1 frags, k-rows 4..67)
//   BS : [p][nt][l15] short8 (16B)          =  4096 B  (sin cols k 64..67; slot[4] = b1[n]/s1
//                                                       -> bias rides the MFMA via aS[4]=1.0;
//                                                       slots 5..7 zero; quad-broadcast)
//   FQ : [p][nt][quad][2] f32x4 (16B)       =  2048 B  (t0={w0[j=0..3]}, t1={w1[j=0..3]},
//                                                       wo[j]=W2o[n]*sq2*s1, n=nt*16+quad*4+j)
//   --- staged to LDS: first 38912 B ---
//   BC : [p][half][lane] short8 (16B)       =  4096 B  (W2 c-col frags; rows>=2 zeroed; global/L2)
#define WS_WB  0
#define WS_BS  32768
#define WS_FQ  36864
#define LDS_BYTES 38912
#define WS_BC  38912
#define WS_BYTES 43008

// ---------------- prep: convert + permute weights into d_ws (16 small blocks) ----
__global__ void prep_kernel(const float* __restrict__ Wx1, const float* __restrict__ bx1,
                            const float* __restrict__ Wx2,
                            const float* __restrict__ Wy1, const float* __restrict__ by1,
                            const float* __restrict__ Wy2,
                            char* __restrict__ ws)
{
  const int b = blockIdx.x;            // 16 blocks: (p, nt)
  const int lane = threadIdx.x;        // 64 threads = 1 wave
  const int p = b >> 3, nt = b & 7;
  const int l15 = lane & 15, quad = lane >> 4;
  const float* W1 = p ? Wy1 : Wx1;
  const float* B1 = p ? by1 : bx1;
  const float* W2 = p ? Wy2 : Wx2;
  const int n = nt * 16 + l15;
  const float* rp = W1 + n * 68;
  short8 bb0, bb1;
  #pragma unroll
  for (int j = 0; j < 8; ++j) {
    bb0[j] = (short)f2bf_rne(rp[4 + quad * 8 + j]);    // K-perm: k<64 -> col 4+k (c dims)
    bb1[j] = (short)f2bf_rne(rp[36 + quad * 8 + j]);   // k 32..63 -> col 36+...
  }
  short8* wb = (short8*)(ws + WS_WB);
  wb[((p * 8 + nt) * 2 + 0) * 64 + lane] = bb0;
  wb[((p * 8 + nt) * 2 + 1) * 64 + lane] = bb1;

  if (quad == 0) {   // sin-col weights (k 64..67) for neuron n; slot 4 carries b1[n]/s1
    const float inv_s1 = 8.24621125123532110f; // sqrt(68)
    short8 t = (short8)0;
    #pragma unroll
    for (int j = 0; j < 4; ++j) t[j] = (short)f2bf_rne(rp[j]);
    t[4] = (short)f2bf_rne(B1[n] * inv_s1);    // pairs with aS[4] = 1.0 in main
    ((short8*)(ws + WS_BS))[(p * 8 + nt) * 16 + l15] = t;
  }

  if (lane < 8) {    // FQ scalars, indexed by the OUTPUT n = nt*16 + quad*4 + j
    const int q = lane >> 1, t = lane & 1;
    const float SQ2 = 1.41421356237309515f;
    const float s1 = 0.121267812518166f;       // 1/sqrt(68)
    float4 v;
    #pragma unroll
    for (int j = 0; j < 4; ++j) {
      const int nn = nt * 16 + q * 4 + j;
      ((float*)&v)[j] = W2[(t ? 192 : 0) + nn] * SQ2 * s1;
    }
    ((float4*)(ws + WS_FQ))[((p * 8 + nt) * 4 + q) * 2 + t] = v;
  }

  if (b < 4) {       // W2 c-columns (128..191); rows l15>=2 zero -> D rows 2..15 = 0
    const int p2 = b >> 1, h = b & 1;
    const float* W2b = p2 ? Wy2 : Wx2;
    short8 bc = (short8)0;
    if (l15 < 2) {
      #pragma unroll
      for (int j = 0; j < 8; ++j)
        bc[j] = (short)f2bf_rne(W2b[l15 * 192 + 128 + h * 32 + quad * 8 + j]);
    }
    ((short8*)(ws + WS_BC))[(p2 * 2 + h) * 64 + lane] = bc;
  }
}

// ------- main: R5 schedule (unroll-1 path loop, late c-part) + 5-DS/nt hot loop ----
__global__ __launch_bounds__(512, 2)
void icb_main(const float* __restrict__ g_coords, const float* __restrict__ g_c,
              const float* __restrict__ g_bx2, const float* __restrict__ g_by2,
              const char* __restrict__ ws, float* __restrict__ g_out)
{
  __shared__ float4 s_tab4[LDS_BYTES / 16];   // 38912 B -> 4 blocks/CU by LDS
  char* s_tab = (char*)s_tab4;

  const int tid  = threadIdx.x;
  const int lane = tid & 63, wave = tid >> 6;          // 8 waves
  const int l15  = lane & 15, quad = lane >> 4;
  const int wbase = blockIdx.x * 256 + wave * 32;      // 2 m-tiles of 16 rows per wave

  // ---- 1. per-row global loads first: latency overlaps staging ----
  float4 ra[2][4]; float2 rco[2];
  #pragma unroll
  for (int mt = 0; mt < 2; ++mt) {
    const int r = wbase + mt * 16 + l15;
    const float4* cr = (const float4*)(g_c + (size_t)r * 64);
    ra[mt][0] = cr[quad * 2];     ra[mt][1] = cr[quad * 2 + 1];
    ra[mt][2] = cr[8 + quad * 2]; ra[mt][3] = cr[8 + quad * 2 + 1];
    rco[mt] = ((const float2*)g_coords)[r];
  }

  // ---- 2. stage the weight table into LDS (once per block) ----
  {
    const float4* src = (const float4*)ws;
    #pragma unroll
    for (int k = 0; k < 5; ++k) {
      const int t = tid + k * 512;                     // 2432 x 16B
      if (t < LDS_BYTES / 16) s_tab4[t] = src[t];
    }
  }

  // ---- 3. pack data frags (B-operands) while staging drains ----
  short8 aC0[2], aC1[2];
  float xold[2], yold[2];
  #pragma unroll
  for (int mt = 0; mt < 2; ++mt) {
    aC0[mt] = pack8f(ra[mt][0], ra[mt][1]);
    aC1[mt] = pack8f(ra[mt][2], ra[mt][3]);
    xold[mt] = rco[mt].x; yold[mt] = rco[mt].y;
  }

  __syncthreads();

  const short8* wb  = (const short8*)(s_tab + WS_WB);
  const short8* wbs = (const short8*)(s_tab + WS_BS);
  const f32x4*  wfq = (const f32x4*) (s_tab + WS_FQ);
  const short8* wbc = (const short8*)(ws + WS_BC);     // small, L2-resident

  const float s2 = 0.0721687836487032f;   // 1/sqrt(192)

  float vin[2], xnew[2], ynew[2], xls[2], yls[2];
  vin[0] = xold[0]; vin[1] = xold[1];

  #pragma unroll 1
  for (int path = 0; path < 2; ++path) {
    const int pb = path * 8;
    const float* b2 = path ? g_by2 : g_bx2;
    const float b20 = b2[0], b21 = b2[1];

    // issue the (L2-resident) W2-c frag loads early; consume after the nt loop
    short8 bc0 = wbc[(path * 2 + 0) * 64 + lane];
    short8 bc1 = wbc[(path * 2 + 1) * 64 + lane];

    // sinusoidal data frag: quad 0 holds k 64..67 = [sin a, sin 2a, cos a, c2a], slot4 = 1.0
    short8 aS[2];
    #pragma unroll
    for (int mt = 0; mt < 2; ++mt) {
      short8 f = (short8)0;
      if (quad == 0) {
        float a = vin[mt] * 0.1f;
        float sa, ca;
        __sincosf(a, &sa, &ca);
        float s2a = 2.0f * sa * ca;
        float c2a = 1.0f - 2.0f * sa * sa;
        f[0] = (short)f2bf_rne(sa); f[1] = (short)f2bf_rne(s2a);
        f[2] = (short)f2bf_rne(ca); f[3] = (short)f2bf_rne(c2a);
        f[4] = (short)0x3F80;              // 1.0 -> picks up b1[n]/s1 from bsw[4]
      }
      aS[mt] = f;
    }

    // hp pair-partials: hp0/hp1[mt] accumulate {j even, j odd} halves separately
    f32x2 hp0[2], hp1[2];
    #pragma unroll
    for (int mt = 0; mt < 2; ++mt) { hp0[mt] = (f32x2)0.f; hp1[mt] = (f32x2)0.f; }

    #pragma unroll 2
    for (int nt = 0; nt < 8; ++nt) {
      short8 bb0 = wb[((pb + nt) * 2 + 0) * 64 + lane];
      short8 bb1 = wb[((pb + nt) * 2 + 1) * 64 + lane];
      short8 bsw = wbs[(pb + nt) * 16 + l15];            // broadcast across quads
      const f32x4* fq = wfq + ((pb + nt) * 4 + quad) * 2;
      f32x4 w0q = fq[0], w1q = fq[1];                    // w = W2*sq2*s1 per (quad,j)
      f32x2 w0lo = {w0q[0], w0q[1]}, w0hi = {w0q[2], w0q[3]};
      f32x2 w1lo = {w1q[0], w1q[1]}, w1hi = {w1q[2], w1q[3]};
      #pragma unroll
      for (int mt = 0; mt < 2; ++mt) {
        f32x4 acc = {0.f, 0.f, 0.f, 0.f};
        acc = __builtin_amdgcn_mfma_f32_16x16x32_bf16(bb0, aC0[mt], acc, 0, 0, 0);
        acc = __builtin_amdgcn_mfma_f32_16x16x32_bf16(bb1, aC1[mt], acc, 0, 0, 0);
        acc = __builtin_amdgcn_mfma_f32_16x16x32_bf16(bsw, aS[mt],  acc, 0, 0, 0);
        // m = max(D, 0.2*D) = leaky(D + b1/s1); true h = s1*m, s1 folded into w*
        f32x2 dlo = {acc[0], acc[1]}, dhi = {acc[2], acc[3]};
        f32x2 mlo = __builtin_elementwise_max(dlo, dlo * 0.2f);
        f32x2 mhi = __builtin_elementwise_max(dhi, dhi * 0.2f);
        hp0[mt] = __builtin_elementwise_fma(mlo, w0lo, hp0[mt]);
        hp0[mt] = __builtin_elementwise_fma(mhi, w0hi, hp0[mt]);
        hp1[mt] = __builtin_elementwise_fma(mlo, w1lo, hp1[mt]);
        hp1[mt] = __builtin_elementwise_fma(mhi, w1hi, hp1[mt]);
      }
    }

    // layer-2 c-part: D[row=o][col=r]; rows>=2 zero by construction
    f32x4 acc8[2];
    #pragma unroll
    for (int mt = 0; mt < 2; ++mt) {
      f32x4 a = {0.f, 0.f, 0.f, 0.f};
      a = __builtin_amdgcn_mfma_f32_16x16x32_bf16(bc0, aC0[mt], a, 0, 0, 0);
      a = __builtin_amdgcn_mfma_f32_16x16x32_bf16(bc1, aC1[mt], a, 0, 0, 0);
      acc8[mt] = a;
    }

    // combine pair-partials + c-part, reduce across the 4 quads (2-stage butterfly)
    #pragma unroll
    for (int mt = 0; mt < 2; ++mt) {
      float h0 = hp0[mt][0] + hp0[mt][1] + acc8[mt][0];
      float h1 = hp1[mt][0] + hp1[mt][1] + acc8[mt][1];
      h0 += __shfl_xor(h0, 16); h0 += __shfl_xor(h0, 32);
      h1 += __shfl_xor(h1, 16); h1 += __shfl_xor(h1, 32);

      float lsraw = fmaf(s2, h0, b20);
      float brow  = fmaf(s2, h1, b21);
      float ls = fminf(fmaxf(lsraw, -5.f), 5.f);
      float e  = __expf(ls);
      if (path == 0) {
        yls[mt]  = ls;
        ynew[mt] = fmaf(yold[mt], e, brow);
        vin[mt]  = ynew[mt];          // y-path sinusoidals use updated y (all lanes have it)
      } else {
        xls[mt]  = ls;
        xnew[mt] = fmaf(xold[mt], e, brow);
      }
    }
  }

  // outputs: warped (x,y) then log_jac, fp32; every lane l15 holds its row's result
  if (lane < 16) {
    #pragma unroll
    for (int mt = 0; mt < 2; ++mt) {
      int R = wbase + mt * 16 + lane;
      float2 pw; pw.x = xnew[mt]; pw.y = ynew[mt];
      reinterpret_cast<float2*>(g_out)[R] = pw;
      g_out[1048576 + R] = xls[mt] + yls[mt];
    }
  }
}

extern "C" void kernel_launch(void* const* d_in, const int* in_sizes, int n_in,
                              void* d_out, int out_size, void* d_ws, size_t ws_size,
                              hipStream_t stream) {
  (void)in_sizes; (void)n_in; (void)out_size; (void)ws_size;
  prep_kernel<<<16, 64, 0, stream>>>(
      (const float*)d_in[2], (const float*)d_in[3], (const float*)d_in[4],
      (const float*)d_in[6], (const float*)d_in[7], (const float*)d_in[8],
      (char*)d_ws);
  icb_main<<<2048, 512, 0, stream>>>(
      (const float*)d_in[0], (const float*)d_in[1],
      (const float*)d_in[5], (const float*)d_in[9],
      (const char*)d_ws, (float*)d_out);
}